// Round 15
// baseline (1677.689 us; speedup 1.0000x reference)
//
#include <hip/hip_runtime.h>
#include <hip/hip_bf16.h>
#include <math.h>

using bf16 = __hip_bfloat16;
typedef __attribute__((ext_vector_type(8))) short short8;
typedef __attribute__((ext_vector_type(4))) float f32x4;
typedef __attribute__((ext_vector_type(16))) float f32x16;

#define NTOKC 2048
#define DM 1024
#define SEQL 512
#define NHEADS 16
#define HDIM 64
#define FFDIM 4096
#define NLAYERS 6
#define VOCAB 32000

__device__ __forceinline__ void gld_lds16(const void* g, void* l) {
  __builtin_amdgcn_global_load_lds((__attribute__((address_space(1))) void*)g,
                                   (__attribute__((address_space(3))) void*)l, 16, 0, 0);
}

// ---------------- GEMM: C = A[M,K] * Bt[N,K]^T ----------------
// 32x32x16 MFMA, BK=64 single-buffer, k-XOR swizzle over 8 slots (best 2-phase).
// A2/a2from: per-z A-base switch. flag 4 + zh==2: write V^T into VT[bh][d][s]
// via per-wave LDS transpose instead of C. Launches using flag 4 must use HH=3.
template<int BM, int BN>
__global__ __launch_bounds__(256, 3) void gemm_k(
    const bf16* __restrict__ A, const bf16* __restrict__ B, void* __restrict__ Cp,
    const float* __restrict__ bias, int K, int lda, int ldb, int ldc,
    long long sAb, long long sAh, long long sBb, long long sBh,
    long long sCb, long long sCh, int HH, int biasStride, float scale, int flags,
    int mTiles, const bf16* __restrict__ A2, int a2from, bf16* __restrict__ VT)
{
  constexpr int WAM = BM/64;
  constexpr int WAN = 4/WAM;
  constexpr int WN  = BN/WAN;
  constexpr int FM  = 2;
  constexpr int FN  = WN/32;
  constexpr int NCA = (BM*64)/2048;
  constexpr int NCB = (BN*64)/2048;
  __shared__ __align__(16) bf16 Smem[BM*64 + BN*64];
  bf16* As = Smem;
  bf16* Bs = Smem + BM*64;
  const int tid = threadIdx.x, w = tid>>6, l = tid&63;
  const int z = blockIdx.z, zb = z/HH, zh = z - zb*HH;
  const bf16* Abase = (zh >= a2from) ? A2 : A;
  const bf16* Ab = Abase + (size_t)zb*sAb + (size_t)zh*sAh;
  const bf16* Bb = B + (size_t)zb*sBb + (size_t)zh*sBh;

  const int nwg = gridDim.x;
  int o = blockIdx.x, idx = o;
  if ((nwg & 7) == 0) idx = (o & 7) * (nwg >> 3) + (o >> 3);   // XCD-chunked, bijective
  const int mt = idx % mTiles, nt = idx / mTiles;              // m fastest within chunk
  const int m0 = mt*BM, n0 = nt*BN;

  const int wm = w / WAN, wn = w % WAN;
  const int lr = l & 31;
  const int lh = l >> 5;

  f32x16 acc[FM][FN];
  #pragma unroll
  for (int i=0;i<FM;i++)
    #pragma unroll
    for (int j=0;j<FN;j++)
      #pragma unroll
      for (int e=0;e<16;e++) acc[i][j][e] = 0.f;

  int rA[NCA], kA[NCA];
  #pragma unroll
  for (int c=0;c<NCA;c++){ int e=c*2048+tid*8; int r=e>>6, k=e&63; rA[c]=r; kA[c]=k ^ ((r&7)<<3); }
  int rB[NCB], kB[NCB];
  #pragma unroll
  for (int c=0;c<NCB;c++){ int e=c*2048+tid*8; int r=e>>6, k=e&63; rB[c]=r; kB[c]=k ^ ((r&7)<<3); }

  for (int kt=0; kt<K; kt+=64) {
    #pragma unroll
    for (int c=0;c<NCA;c++)
      gld_lds16(Ab + (size_t)(m0+rA[c])*lda + kt + kA[c], (char*)As + c*4096 + w*1024);
    #pragma unroll
    for (int c=0;c<NCB;c++)
      gld_lds16(Bb + (size_t)(n0+rB[c])*ldb + kt + kB[c], (char*)Bs + c*4096 + w*1024);
    __syncthreads();
    #pragma unroll
    for (int kq=0; kq<4; kq++) {
      const int kk = kq*16 + lh*8;
      short8 a_[FM], b_[FN];
      #pragma unroll
      for (int i=0;i<FM;i++) {
        const int row = wm*64 + i*32 + lr;
        a_[i] = *(const short8*)(As + row*64 + (kk ^ ((row&7)<<3)));
      }
      #pragma unroll
      for (int j=0;j<FN;j++) {
        const int row = wn*WN + j*32 + lr;
        b_[j] = *(const short8*)(Bs + row*64 + (kk ^ ((row&7)<<3)));
      }
      #pragma unroll
      for (int i=0;i<FM;i++)
        #pragma unroll
        for (int j=0;j<FN;j++)
          acc[i][j] = __builtin_amdgcn_mfma_f32_32x32x16_bf16(a_[i], b_[j], acc[i][j], 0,0,0);
    }
    __syncthreads();
  }

  const float* brow = bias ? (bias + (size_t)z*biasStride) : nullptr;

  // ---- V^T epilogue: per-wave 64x64 LDS transpose -> VT[bh][d][s] ----
  if (BM==128 && BN==128 && (flags & 4) && zh == 2) {
    bf16* T = Smem + w*4096;                         // own 64x64 region (8 KB)
    #pragma unroll
    for (int i=0;i<FM;i++) {
      #pragma unroll
      for (int j=0;j<FN;j++) {
        const int cl = j*32 + lr;                    // local col (=d) 0..63
        const float bv = brow ? brow[n0 + wn*WN + cl] : 0.f;
        #pragma unroll
        for (int r=0;r<16;r++) {
          const int sl = i*32 + 4*lh + (r&3) + 8*(r>>2);   // local row (=s) 0..63
          T[sl*64 + (cl ^ (sl & 63))] = __float2bfloat16(acc[i][j][r]*scale + bv);
        }
      }
    }
    asm volatile("s_waitcnt lgkmcnt(0)" ::: "memory");   // this wave's ds_writes done
    __builtin_amdgcn_sched_barrier(0);
    const int token0 = m0 + wm*64;
    const int bb = token0 >> 9, sbase = token0 & 511;
    const int h = (n0 + wn*WN) >> 6;                 // one head per wave region
    #pragma unroll
    for (int it=0; it<8; ++it) {
      const int crow = it*8 + (l>>3);                // d
      const int s0 = (l&7)*8;
      short8 v8;
      #pragma unroll
      for (int k=0;k<8;k++) {
        const int s = s0 + k;
        v8[k] = *(const short*)&T[s*64 + (crow ^ (s & 63))];
      }
      *(short8*)(VT + (((size_t)(bb*16 + h)*64 + crow)*512 + sbase + s0)) = v8;
    }
    return;                                          // uniform branch per block
  }

  const bool obf = flags & 1, orl = flags & 2;
  const size_t coff = (size_t)zb*sCb + (size_t)zh*sCh;
  #pragma unroll
  for (int i=0;i<FM;i++) {
    #pragma unroll
    for (int j=0;j<FN;j++) {
      const int col = n0 + wn*WN + j*32 + lr;
      const float bv = brow ? brow[col] : 0.f;
      const int row0 = m0 + wm*64 + i*32 + 4*lh;
      #pragma unroll
      for (int r=0;r<16;r++) {
        const int row = row0 + (r&3) + 8*(r>>2);
        float v = acc[i][j][r]*scale + bv;
        if (orl) v = fmaxf(v, 0.f);
        const size_t off = coff + (size_t)row*ldc + col;
        if (obf) ((bf16*)Cp)[off] = __float2bfloat16(v);
        else     ((float*)Cp)[off] = v;
      }
    }
  }
}

// ---------------- fused flash attention ----------------
// grid: (q-tiles=8, bh=64). 4 waves (256 thr); wave owns 16 q-rows; KV tiles of 64.
// TWO staging chunks per K/V tile (256 thr x 8 elems = rows 0-31; +256 = rows 32-63).
template<int CAUSAL>
__global__ __launch_bounds__(256, 4) void flash_k(
    const bf16* __restrict__ Qg, const bf16* __restrict__ Kg,
    const bf16* __restrict__ Vt, bf16* __restrict__ Og)
{
  constexpr int PADK = 72;
  __shared__ __align__(16) bf16 Ks[64*PADK];
  __shared__ __align__(16) bf16 Vs[64*PADK];
  __shared__ __align__(16) bf16 Ps[4*16*PADK];
  const int tid = threadIdx.x, w = tid>>6, l = tid&63;
  const int qt = blockIdx.x, bh = blockIdx.y;
  const int b = bh>>4, h = bh&15;
  const int q0 = qt*64;
  const int lr = l&15, lg = l>>4;

  const bf16* qrow = Qg + (size_t)(b*SEQL + q0 + w*16 + lr)*DM + h*HDIM + lg*8;
  short8 qf0 = *(const short8*)(qrow);
  short8 qf1 = *(const short8*)(qrow + 32);

  const f32x4 vzero = {0.f,0.f,0.f,0.f};
  f32x4 Oa[4];
  float mrow[4], lrow[4];
  #pragma unroll
  for (int j=0;j<4;j++) Oa[j] = vzero;
  #pragma unroll
  for (int r=0;r<4;r++){ mrow[r] = -INFINITY; lrow[r] = 0.f; }

  const int ntiles = CAUSAL ? (qt+1) : (SEQL/64);
  const int c0 = tid, c1 = tid + 256;
  const int r0_ = c0>>3, o0_ = (c0&7)*8, r1_ = c1>>3, o1_ = (c1&7)*8;

  short8 s0,s1,s2,s3;
  {
    s0 = *(const short8*)(Kg + (size_t)(b*SEQL + r0_)*DM + h*HDIM + o0_);
    s1 = *(const short8*)(Kg + (size_t)(b*SEQL + r1_)*DM + h*HDIM + o1_);
    s2 = *(const short8*)(Vt + ((size_t)bh*HDIM + r0_)*SEQL + o0_);
    s3 = *(const short8*)(Vt + ((size_t)bh*HDIM + r1_)*SEQL + o1_);
  }

  for (int t=0; t<ntiles; ++t) {
    __syncthreads();
    *(short8*)(Ks + r0_*PADK + o0_) = s0;
    *(short8*)(Ks + r1_*PADK + o1_) = s1;
    *(short8*)(Vs + r0_*PADK + o0_) = s2;
    *(short8*)(Vs + r1_*PADK + o1_) = s3;
    __syncthreads();
    if (t+1 < ntiles) {
      const int kv1 = (t+1)*64;
      s0 = *(const short8*)(Kg + (size_t)(b*SEQL + kv1 + r0_)*DM + h*HDIM + o0_);
      s1 = *(const short8*)(Kg + (size_t)(b*SEQL + kv1 + r1_)*DM + h*HDIM + o1_);
      s2 = *(const short8*)(Vt + ((size_t)bh*HDIM + r0_)*SEQL + kv1 + o0_);
      s3 = *(const short8*)(Vt + ((size_t)bh*HDIM + r1_)*SEQL + kv1 + o1_);
    }

    f32x4 sa[4];
    #pragma unroll
    for (int jg=0;jg<4;jg++) {
      short8 kb0 = *(const short8*)(Ks + (jg*16+lr)*PADK + lg*8);
      short8 kb1 = *(const short8*)(Ks + (jg*16+lr)*PADK + 32 + lg*8);
      sa[jg] = __builtin_amdgcn_mfma_f32_16x16x32_bf16(qf0, kb0, vzero, 0,0,0);
      sa[jg] = __builtin_amdgcn_mfma_f32_16x16x32_bf16(qf1, kb1, sa[jg], 0,0,0);
    }

    float pv[4][4];
    #pragma unroll
    for (int jg=0;jg<4;jg++)
      #pragma unroll
      for (int r=0;r<4;r++) {
        float sv = sa[jg][r]*0.125f;
        if (CAUSAL && t==ntiles-1) {
          if (jg*16+lr > w*16+lg*4+r) sv = -INFINITY;
        }
        pv[jg][r] = sv;
      }
    float tm[4], sf[4], rs[4];
    #pragma unroll
    for (int r=0;r<4;r++) {
      float mx = fmaxf(fmaxf(pv[0][r],pv[1][r]), fmaxf(pv[2][r],pv[3][r]));
      #pragma unroll
      for (int o=1;o<16;o<<=1) mx = fmaxf(mx, __shfl_xor(mx, o));
      tm[r] = fmaxf(mrow[r], mx);
      sf[r] = __expf(mrow[r]-tm[r]);
      mrow[r] = tm[r];
    }
    #pragma unroll
    for (int r=0;r<4;r++) {
      float acc = 0.f;
      #pragma unroll
      for (int jg=0;jg<4;jg++) { float e = __expf(pv[jg][r]-tm[r]); pv[jg][r]=e; acc += e; }
      #pragma unroll
      for (int o=1;o<16;o<<=1) acc += __shfl_xor(acc, o);
      rs[r] = acc;
      lrow[r] = lrow[r]*sf[r] + rs[r];
    }
    #pragma unroll
    for (int jg=0;jg<4;jg++)
      #pragma unroll
      for (int r=0;r<4;r++) Oa[jg][r] *= sf[r];

    bf16* pw = Ps + w*16*PADK;
    #pragma unroll
    for (int jg=0;jg<4;jg++)
      #pragma unroll
      for (int r=0;r<4;r++)
        pw[(lg*4+r)*PADK + jg*16+lr] = __float2bfloat16(pv[jg][r]);
    asm volatile("s_waitcnt lgkmcnt(0)" ::: "memory");
    __builtin_amdgcn_sched_barrier(0);
    short8 pa0 = *(const short8*)(pw + lr*PADK + lg*8);
    short8 pa1 = *(const short8*)(pw + lr*PADK + 32 + lg*8);
    #pragma unroll
    for (int jg=0;jg<4;jg++) {
      short8 vb0 = *(const short8*)(Vs + (jg*16+lr)*PADK + lg*8);
      short8 vb1 = *(const short8*)(Vs + (jg*16+lr)*PADK + 32 + lg*8);
      Oa[jg] = __builtin_amdgcn_mfma_f32_16x16x32_bf16(pa0, vb0, Oa[jg], 0,0,0);
      Oa[jg] = __builtin_amdgcn_mfma_f32_16x16x32_bf16(pa1, vb1, Oa[jg], 0,0,0);
    }
  }

  #pragma unroll
  for (int r=0;r<4;r++) {
    const float inv = 1.f/lrow[r];
    const size_t rb = (size_t)(b*SEQL + q0 + w*16 + lg*4 + r)*DM + h*HDIM;
    #pragma unroll
    for (int jg=0;jg<4;jg++)
      Og[rb + jg*16 + lr] = __float2bfloat16(Oa[jg][r]*inv);
  }
}

// ---------------- embedding + pos-enc AND enc f32->bf16 (merged prologue) ----------
__global__ __launch_bounds__(256) void embed2_k(const int* __restrict__ dec, const float* __restrict__ emb,
    const float* __restrict__ enc, float* __restrict__ x32, bf16* __restrict__ x16,
    bf16* __restrict__ enc16)
{
  const int bid = blockIdx.x;
  if (bid < 8192) {
    const int idx = bid*256 + threadIdx.x;
    const int d = idx & (DM-1), tok = idx >> 10, s = tok & (SEQL-1);
    const float e = emb[(size_t)dec[tok]*DM + d];
    const float den = powf(10000.f, (float)(d & ~1) * (1.f/(float)DM));
    const float ang = (float)s / den;
    const float pe = (d&1) ? cosf(ang) : sinf(ang);
    const float vv = e + pe;
    x32[idx] = vv; x16[idx] = __float2bfloat16(vv);
  } else {
    const int i = (bid-8192)*256 + threadIdx.x;
    enc16[i] = __float2bfloat16(enc[i]);
  }
}

// ---------------- weight transpose + f32->bf16: dst[N][K] = src[K][N] ----------------
__global__ __launch_bounds__(256) void trans_k(const float* __restrict__ src, bf16* __restrict__ dst, int K, int N)
{
  __shared__ float t[32][33];
  const int n0 = blockIdx.x*32, k0 = blockIdx.y*32;
  const int tx = threadIdx.x&31, ty = threadIdx.x>>5;
  #pragma unroll
  for (int i=0;i<4;i++) t[ty+i*8][tx] = src[(size_t)(k0+ty+i*8)*N + n0+tx];
  __syncthreads();
  #pragma unroll
  for (int i=0;i<4;i++) dst[(size_t)(n0+ty+i*8)*K + k0+tx] = __float2bfloat16(t[tx][ty+i*8]);
}

// ---------------- per-layer multi-matrix transpose (fallback path) ----------------
struct TPack { const float* src[10]; bf16* dst[10]; int K[10]; int N[10]; int tile0[10]; };
__global__ __launch_bounds__(256) void transm_k(TPack p)
{
  __shared__ float t[32][33];
  const int id = blockIdx.x;
  int mi = 0;
  #pragma unroll
  for (int i=1;i<10;i++) if (id >= p.tile0[i]) mi = i;
  const float* src = p.src[mi]; bf16* dst = p.dst[mi];
  const int K = p.K[mi], N = p.N[mi];
  const int local = id - p.tile0[mi];
  const int ntn = N >> 5;
  const int nt = local % ntn, kt = local / ntn;
  const int n0 = nt*32, k0 = kt*32;
  const int tx = threadIdx.x&31, ty = threadIdx.x>>5;
  #pragma unroll
  for (int i=0;i<4;i++) t[ty+i*8][tx] = src[(size_t)(k0+ty+i*8)*N + n0+tx];
  __syncthreads();
  #pragma unroll
  for (int i=0;i<4;i++) dst[(size_t)(n0+ty+i*8)*K + k0+tx] = __float2bfloat16(t[tx][ty+i*8]);
}

// ---------------- ALL-layer weight transpose (one prologue launch) ----------------
// 16384 tiles/layer: [0,8192) attn (8 mats x 1024), [8192,12288) F1, [12288,16384) F2.
struct TAll { const float* a[8]; const float* f1; const float* f2;
              bf16* dA; bf16* dF1; bf16* dF2; };
__global__ __launch_bounds__(256) void transall_k(TAll p)
{
  __shared__ float t[32][33];
  const int id = blockIdx.x;
  const int layer = id >> 14;
  const int local = id & 16383;
  const float* src; bf16* dst; int K, N, tt;
  if (local < 8192) {
    const int mi = local >> 10;
    tt = local & 1023;
    src = p.a[mi] + (size_t)layer*DM*DM;
    dst = p.dA + ((size_t)layer*8 + mi)*DM*DM;
    K = DM; N = DM;
  } else if (local < 12288) {
    tt = local - 8192;
    src = p.f1 + (size_t)layer*DM*FFDIM;
    dst = p.dF1 + (size_t)layer*DM*FFDIM;
    K = DM; N = FFDIM;
  } else {
    tt = local - 12288;
    src = p.f2 + (size_t)layer*FFDIM*DM;
    dst = p.dF2 + (size_t)layer*FFDIM*DM;
    K = FFDIM; N = DM;
  }
  const int ntn = N >> 5;
  const int nt = tt % ntn, kt = tt / ntn;
  const int n0 = nt*32, k0 = kt*32;
  const int tx = threadIdx.x&31, ty = threadIdx.x>>5;
  #pragma unroll
  for (int i=0;i<4;i++) t[ty+i*8][tx] = src[(size_t)(k0+ty+i*8)*N + n0+tx];
  __syncthreads();
  #pragma unroll
  for (int i=0;i<4;i++) dst[(size_t)(n0+ty+i*8)*K + k0+tx] = __float2bfloat16(t[tx][ty+i*8]);
}

// ---------------- upfront bias packing: [L][ sa_q,sa_k,sa_v, ca_q,ca_k,ca_v ][1024] ----
struct BiasSrc { const float* s[6]; float* out; };
__global__ __launch_bounds__(256) void biaspack_k(BiasSrc p)
{
  const int i = blockIdx.x*256 + threadIdx.x;          // < L*6*1024
  const int l = i / 6144, j = i - l*6144;
  const int m = j >> 10, c = j & 1023;
  p.out[i] = p.s[m][(size_t)l*DM + c];
}

// ---------------- fused residual-add + bias + K-split-sum + LayerNorm ----------------
__global__ __launch_bounds__(256) void ln_k(const float* __restrict__ a, const float* __restrict__ a2,
    const float* __restrict__ gb, const float* __restrict__ r,
    const float* __restrict__ g, const float* __restrict__ be,
    float* __restrict__ y32, bf16* __restrict__ y16)
{
  const int row = blockIdx.x, t = threadIdx.x;
  const size_t base = (size_t)row*DM;
  float v[4]; float s = 0.f;
  #pragma unroll
  for (int i=0;i<4;i++){ int c=t+i*256; v[i] = a[base+c] + a2[base+c] + gb[c] + r[base+c]; s += v[i]; }
  __shared__ float red[8];
  #pragma unroll
  for (int o=32;o>0;o>>=1) s += __shfl_down(s,o);
  if ((t&63)==0) red[t>>6]=s;
  __syncthreads();
  const float mean = (red[0]+red[1]+red[2]+red[3]) * (1.f/1024.f);
  float vs = 0.f;
  #pragma unroll
  for (int i=0;i<4;i++){ float d=v[i]-mean; vs += d*d; }
  #pragma unroll
  for (int o=32;o>0;o>>=1) vs += __shfl_down(vs,o);
  if ((t&63)==0) red[4+(t>>6)]=vs;
  __syncthreads();
  const float var = (red[4]+red[5]+red[6]+red[7]) * (1.f/1024.f);
  const float rstd = rsqrtf(var + 1e-10f);
  #pragma unroll
  for (int i=0;i<4;i++){
    int c=t+i*256;
    float y = g[c]*(v[i]-mean)*rstd + be[c];
    y32[base+c] = y; y16[base+c] = __float2bfloat16(y);
  }
}

extern "C" void kernel_launch(void* const* d_in, const int* in_sizes, int n_in,
                              void* d_out, int out_size, void* d_ws, size_t ws_size,
                              hipStream_t stream)
{
  (void)in_sizes; (void)n_in; (void)out_size;
  const int*   dec    = (const int*)  d_in[0];
  const float* enc    = (const float*)d_in[1];
  const float* emb    = (const float*)d_in[4];
  const float* sa_w[4] = { (const float*)d_in[5], (const float*)d_in[7], (const float*)d_in[9],  (const float*)d_in[11] };
  const float* sa_b[4] = { (const float*)d_in[6], (const float*)d_in[8], (const float*)d_in[10], (const float*)d_in[12] };
  const float* ca_w[4] = { (const float*)d_in[13], (const float*)d_in[15], (const float*)d_in[17], (const float*)d_in[19] };
  const float* ca_b[4] = { (const float*)d_in[14], (const float*)d_in[16], (const float*)d_in[18], (const float*)d_in[20] };
  const float* ffn_w1 = (const float*)d_in[21];
  const float* ffn_b1 = (const float*)d_in[22];
  const float* ffn_w2 = (const float*)d_in[23];
  const float* ffn_b2 = (const float*)d_in[24];
  const float* ln_g[3] = { (const float*)d_in[25], (const float*)d_in[27], (const float*)d_in[29] };
  const float* ln_b[3] = { (const float*)d_in[26], (const float*)d_in[28], (const float*)d_in[30] };
  const float* w_out  = (const float*)d_in[31];
  const float* b_out  = (const float*)d_in[32];
  float* out = (float*)d_out;

  char* p = (char*)d_ws;
  auto alloc = [&](size_t b)->char* { char* r=p; p += (b+255)&~(size_t)255; return r; };
  bf16* x16   = (bf16*)alloc((size_t)NTOKC*DM*2);
  bf16* enc16 = (bf16*)alloc((size_t)NTOKC*DM*2);
  bf16* qkv   = (bf16*)alloc((size_t)3*NTOKC*DM*2);
  bf16* ctx   = (bf16*)alloc((size_t)NTOKC*DM*2);
  bf16* vt    = (bf16*)alloc((size_t)64*HDIM*SEQL*2);
  bf16* mid   = (bf16*)alloc((size_t)NTOKC*FFDIM*2);
  bf16* wtO   = (bf16*)alloc((size_t)VOCAB*DM*2);
  float* x32  = (float*)alloc((size_t)NTOKC*DM*4);
  float* aout = (float*)alloc((size_t)2*NTOKC*DM*4);   // two K-split halves
  float* biasAll = (float*)alloc((size_t)NLAYERS*6*DM*4);
  float* aout2 = aout + (size_t)NTOKC*DM;

  // weight buffers: all-layer (one prologue transpose) if workspace allows, else per-layer
  const size_t usedFixed = (size_t)(p - (char*)d_ws);
  const size_t needFull = ((size_t)NLAYERS*8*DM*DM + (size_t)2*NLAYERS*DM*FFDIM)*2 + 1024;
  const bool fullw = (ws_size > usedFixed) && (ws_size - usedFixed >= needFull);
  bf16 *wtA, *wtF1, *wtF2;
  if (fullw) {
    wtA  = (bf16*)alloc((size_t)NLAYERS*8*DM*DM*2);
    wtF1 = (bf16*)alloc((size_t)NLAYERS*DM*FFDIM*2);
    wtF2 = (bf16*)alloc((size_t)NLAYERS*FFDIM*DM*2);
  } else {
    wtA  = (bf16*)alloc((size_t)8*DM*DM*2);
    wtF1 = (bf16*)alloc((size_t)DM*FFDIM*2);
    wtF2 = (bf16*)alloc((size_t)FFDIM*DM*2);
  }
  if ((size_t)(p - (char*)d_ws) > ws_size) return;

  embed2_k<<<16384,256,0,stream>>>(dec, emb, enc, x32, x16, enc16);
  trans_k<<<dim3(VOCAB/32, DM/32),256,0,stream>>>(w_out, wtO, DM, VOCAB);
  {
    BiasSrc bs;
    bs.s[0]=sa_b[0]; bs.s[1]=sa_b[1]; bs.s[2]=sa_b[2];
    bs.s[3]=ca_b[0]; bs.s[4]=ca_b[1]; bs.s[5]=ca_b[2];
    bs.out = biasAll;
    biaspack_k<<<(NLAYERS*6*DM)/256,256,0,stream>>>(bs);
  }
  if (fullw) {
    TAll ta;
    for (int i=0;i<4;i++){ ta.a[i] = sa_w[i]; ta.a[4+i] = ca_w[i]; }
    ta.f1 = ffn_w1; ta.f2 = ffn_w2;
    ta.dA = wtA; ta.dF1 = wtF1; ta.dF2 = wtF2;
    transall_k<<<NLAYERS*16384,256,0,stream>>>(ta);
  }

  for (int l=0; l<NLAYERS; ++l) {
    bf16* wtA_l  = wtA  + (fullw ? (size_t)l*8*DM*DM    : 0);
    bf16* wtF1_l = wtF1 + (fullw ? (size_t)l*DM*FFDIM   : 0);
    bf16* wtF2_l = wtF2 + (fullw ? (size_t)l*FFDIM*DM   : 0);
    if (!fullw) {
      TPack tp;
      for (int i=0;i<4;i++){ tp.src[i]   = sa_w[i] + (size_t)l*DM*DM; tp.dst[i]   = wtA_l + (size_t)i*DM*DM;
                             tp.K[i]=DM; tp.N[i]=DM; tp.tile0[i]=i*1024; }
      for (int i=0;i<4;i++){ tp.src[4+i] = ca_w[i] + (size_t)l*DM*DM; tp.dst[4+i] = wtA_l + (size_t)(4+i)*DM*DM;
                             tp.K[4+i]=DM; tp.N[4+i]=DM; tp.tile0[4+i]=(4+i)*1024; }
      tp.src[8]=ffn_w1 + (size_t)l*DM*FFDIM; tp.dst[8]=wtF1_l; tp.K[8]=DM; tp.N[8]=FFDIM; tp.tile0[8]=8192;
      tp.src[9]=ffn_w2 + (size_t)l*FFDIM*DM; tp.dst[9]=wtF2_l; tp.K[9]=FFDIM; tp.N[9]=DM; tp.tile0[9]=12288;
      transm_k<<<16384,256,0,stream>>>(tp);
    }
    const float* biasL = biasAll + (size_t)l*6*DM;

    // ---- self attention: QKV batched (z=3, HH=3 so zh=z; V -> vt) ----
    gemm_k<128,128><<<dim3(128,1,3),256,0,stream>>>(x16, wtA_l, qkv, biasL,
        DM, DM, DM, DM, 0,0, 0,(long long)DM*DM, 0,(long long)NTOKC*DM, 3, DM, 1.f, 1|4, 16, x16, 9, vt);
    flash_k<1><<<dim3(SEQL/64, 64),256,0,stream>>>(qkv, qkv + (size_t)NTOKC*DM, vt, ctx);
    gemm_k<64,128><<<dim3(256,1,2),256,0,stream>>>(ctx, wtA_l + (size_t)3*DM*DM, aout, nullptr,
        512, DM, DM, DM, 0,512, 0,512, 0,(long long)NTOKC*DM, 2, 0, 1.f, 0, 32, ctx, 9, nullptr);
    ln_k<<<2048,256,0,stream>>>(aout, aout2, sa_b[3]+l*DM, x32, ln_g[0]+l*DM, ln_b[0]+l*DM, x32, x16);

    // ---- cross attention: Q(x16) + K,V(enc16) merged z=3; V -> vt ----
    gemm_k<128,128><<<dim3(128,1,3),256,0,stream>>>(x16, wtA_l + (size_t)4*DM*DM, qkv, biasL + 3*DM,
        DM, DM, DM, DM, 0,0, 0,(long long)DM*DM, 0,(long long)NTOKC*DM, 3, DM, 1.f, 1|4, 16, enc16, 1, vt);
    flash_k<0><<<dim3(SEQL/64, 64),256,0,stream>>>(qkv, qkv + (size_t)NTOKC*DM, vt, ctx);
    gemm_k<64,128><<<dim3(256,1,2),256,0,stream>>>(ctx, wtA_l + (size_t)7*DM*DM, aout, nullptr,
        512, DM, DM, DM, 0,512, 0,512, 0,(long long)NTOKC*DM, 2, 0, 1.f, 0, 32, ctx, 9, nullptr);
    ln_k<<<2048,256,0,stream>>>(aout, aout2, ca_b[3]+l*DM, x32, ln_g[1]+l*DM, ln_b[1]+l*DM, x32, x16);

    // ---- ffn ----
    gemm_k<128,128><<<dim3(512,1,1),256,0,stream>>>(x16, wtF1_l, mid, ffn_b1 + (size_t)l*FFDIM,
        DM, DM, DM, FFDIM, 0,0,0,0,0,0, 1, 0, 1.f, 1|2, 16, x16, 9, nullptr);
    gemm_k<64,128><<<dim3(256,1,2),256,0,stream>>>(mid, wtF2_l, aout, nullptr,
        2048, FFDIM, FFDIM, DM, 0,2048, 0,2048, 0,(long long)NTOKC*DM, 2, 0, 1.f, 0, 32, mid, 9, nullptr);
    ln_k<<<2048,256,0,stream>>>(aout, aout2, ffn_b2 + (size_t)l*DM, x32, ln_g[2]+l*DM, ln_b[2]+l*DM, x32, x16);
  }

  gemm_k<128,128><<<dim3(4000,1,1),256,0,stream>>>(x16, wtO, out, b_out,
      DM, DM, DM, VOCAB, 0,0,0,0,0,0, 1, 0, 1.f, 0, 16, x16, 9, nullptr);
}

// Round 16
// 1519.431 us; speedup vs baseline: 1.1042x; 1.1042x over previous
//
#include <hip/hip_runtime.h>
#include <hip/hip_bf16.h>
#include <math.h>

using bf16 = __hip_bfloat16;
typedef __attribute__((ext_vector_type(8))) short short8;
typedef __attribute__((ext_vector_type(4))) float f32x4;
typedef __attribute__((ext_vector_type(16))) float f32x16;

#define NTOKC 2048
#define DM 1024
#define SEQL 512
#define NHEADS 16
#define HDIM 64
#define FFDIM 4096
#define NLAYERS 6
#define VOCAB 32000

__device__ __forceinline__ void gld_lds16(const void* g, void* l) {
  __builtin_amdgcn_global_load_lds((__attribute__((address_space(1))) void*)g,
                                   (__attribute__((address_space(3))) void*)l, 16, 0, 0);
}

// ---------------- GEMM: C = A[M,K] * Bt[N,K]^T ----------------
// 32x32x16 MFMA, BK=64 single-buffer, k-XOR swizzle over 8 slots (best 2-phase).
// A2/a2from: per-z A-base switch. flag 4 + zh==2: write V^T into VT[bh][d][s]
// via per-wave LDS transpose instead of C. Launches using flag 4 must use HH=3.
// NOTE R15 lesson: weights must be converted per-layer (producer->consumer
// L3 locality); all-layer upfront conversion cost +159us.
template<int BM, int BN>
__global__ __launch_bounds__(256, 3) void gemm_k(
    const bf16* __restrict__ A, const bf16* __restrict__ B, void* __restrict__ Cp,
    const float* __restrict__ bias, int K, int lda, int ldb, int ldc,
    long long sAb, long long sAh, long long sBb, long long sBh,
    long long sCb, long long sCh, int HH, int biasStride, float scale, int flags,
    int mTiles, const bf16* __restrict__ A2, int a2from, bf16* __restrict__ VT)
{
  constexpr int WAM = BM/64;
  constexpr int WAN = 4/WAM;
  constexpr int WN  = BN/WAN;
  constexpr int FM  = 2;
  constexpr int FN  = WN/32;
  constexpr int NCA = (BM*64)/2048;
  constexpr int NCB = (BN*64)/2048;
  __shared__ __align__(16) bf16 Smem[BM*64 + BN*64];
  bf16* As = Smem;
  bf16* Bs = Smem + BM*64;
  const int tid = threadIdx.x, w = tid>>6, l = tid&63;
  const int z = blockIdx.z, zb = z/HH, zh = z - zb*HH;
  const bf16* Abase = (zh >= a2from) ? A2 : A;
  const bf16* Ab = Abase + (size_t)zb*sAb + (size_t)zh*sAh;
  const bf16* Bb = B + (size_t)zb*sBb + (size_t)zh*sBh;

  const int nwg = gridDim.x;
  int o = blockIdx.x, idx = o;
  if ((nwg & 7) == 0) idx = (o & 7) * (nwg >> 3) + (o >> 3);   // XCD-chunked, bijective
  const int mt = idx % mTiles, nt = idx / mTiles;              // m fastest within chunk
  const int m0 = mt*BM, n0 = nt*BN;

  const int wm = w / WAN, wn = w % WAN;
  const int lr = l & 31;
  const int lh = l >> 5;

  f32x16 acc[FM][FN];
  #pragma unroll
  for (int i=0;i<FM;i++)
    #pragma unroll
    for (int j=0;j<FN;j++)
      #pragma unroll
      for (int e=0;e<16;e++) acc[i][j][e] = 0.f;

  int rA[NCA], kA[NCA];
  #pragma unroll
  for (int c=0;c<NCA;c++){ int e=c*2048+tid*8; int r=e>>6, k=e&63; rA[c]=r; kA[c]=k ^ ((r&7)<<3); }
  int rB[NCB], kB[NCB];
  #pragma unroll
  for (int c=0;c<NCB;c++){ int e=c*2048+tid*8; int r=e>>6, k=e&63; rB[c]=r; kB[c]=k ^ ((r&7)<<3); }

  for (int kt=0; kt<K; kt+=64) {
    #pragma unroll
    for (int c=0;c<NCA;c++)
      gld_lds16(Ab + (size_t)(m0+rA[c])*lda + kt + kA[c], (char*)As + c*4096 + w*1024);
    #pragma unroll
    for (int c=0;c<NCB;c++)
      gld_lds16(Bb + (size_t)(n0+rB[c])*ldb + kt + kB[c], (char*)Bs + c*4096 + w*1024);
    __syncthreads();
    #pragma unroll
    for (int kq=0; kq<4; kq++) {
      const int kk = kq*16 + lh*8;
      short8 a_[FM], b_[FN];
      #pragma unroll
      for (int i=0;i<FM;i++) {
        const int row = wm*64 + i*32 + lr;
        a_[i] = *(const short8*)(As + row*64 + (kk ^ ((row&7)<<3)));
      }
      #pragma unroll
      for (int j=0;j<FN;j++) {
        const int row = wn*WN + j*32 + lr;
        b_[j] = *(const short8*)(Bs + row*64 + (kk ^ ((row&7)<<3)));
      }
      #pragma unroll
      for (int i=0;i<FM;i++)
        #pragma unroll
        for (int j=0;j<FN;j++)
          acc[i][j] = __builtin_amdgcn_mfma_f32_32x32x16_bf16(a_[i], b_[j], acc[i][j], 0,0,0);
    }
    __syncthreads();
  }

  const float* brow = bias ? (bias + (size_t)z*biasStride) : nullptr;

  // ---- V^T epilogue: per-wave 64x64 LDS transpose -> VT[bh][d][s] ----
  if (BM==128 && BN==128 && (flags & 4) && zh == 2) {
    bf16* T = Smem + w*4096;                         // own 64x64 region (8 KB)
    #pragma unroll
    for (int i=0;i<FM;i++) {
      #pragma unroll
      for (int j=0;j<FN;j++) {
        const int cl = j*32 + lr;                    // local col (=d) 0..63
        const float bv = brow ? brow[n0 + wn*WN + cl] : 0.f;
        #pragma unroll
        for (int r=0;r<16;r++) {
          const int sl = i*32 + 4*lh + (r&3) + 8*(r>>2);   // local row (=s) 0..63
          T[sl*64 + (cl ^ (sl & 63))] = __float2bfloat16(acc[i][j][r]*scale + bv);
        }
      }
    }
    asm volatile("s_waitcnt lgkmcnt(0)" ::: "memory");   // this wave's ds_writes done
    __builtin_amdgcn_sched_barrier(0);
    const int token0 = m0 + wm*64;
    const int bb = token0 >> 9, sbase = token0 & 511;
    const int h = (n0 + wn*WN) >> 6;                 // one head per wave region
    #pragma unroll
    for (int it=0; it<8; ++it) {
      const int crow = it*8 + (l>>3);                // d
      const int s0 = (l&7)*8;
      short8 v8;
      #pragma unroll
      for (int k=0;k<8;k++) {
        const int s = s0 + k;
        v8[k] = *(const short*)&T[s*64 + (crow ^ (s & 63))];
      }
      *(short8*)(VT + (((size_t)(bb*16 + h)*64 + crow)*512 + sbase + s0)) = v8;
    }
    return;                                          // uniform branch per block
  }

  const bool obf = flags & 1, orl = flags & 2;
  const size_t coff = (size_t)zb*sCb + (size_t)zh*sCh;
  #pragma unroll
  for (int i=0;i<FM;i++) {
    #pragma unroll
    for (int j=0;j<FN;j++) {
      const int col = n0 + wn*WN + j*32 + lr;
      const float bv = brow ? brow[col] : 0.f;
      const int row0 = m0 + wm*64 + i*32 + 4*lh;
      #pragma unroll
      for (int r=0;r<16;r++) {
        const int row = row0 + (r&3) + 8*(r>>2);
        float v = acc[i][j][r]*scale + bv;
        if (orl) v = fmaxf(v, 0.f);
        const size_t off = coff + (size_t)row*ldc + col;
        if (obf) ((bf16*)Cp)[off] = __float2bfloat16(v);
        else     ((float*)Cp)[off] = v;
      }
    }
  }
}

// ---------------- fused flash attention ----------------
// grid: (q-tiles=8, bh=64). 4 waves (256 thr); wave owns 16 q-rows; KV tiles of 64.
// TWO staging chunks per K/V tile (256 thr x 8 elems = rows 0-31; +256 = rows 32-63).
template<int CAUSAL>
__global__ __launch_bounds__(256, 4) void flash_k(
    const bf16* __restrict__ Qg, const bf16* __restrict__ Kg,
    const bf16* __restrict__ Vt, bf16* __restrict__ Og)
{
  constexpr int PADK = 72;
  __shared__ __align__(16) bf16 Ks[64*PADK];
  __shared__ __align__(16) bf16 Vs[64*PADK];
  __shared__ __align__(16) bf16 Ps[4*16*PADK];
  const int tid = threadIdx.x, w = tid>>6, l = tid&63;
  const int qt = blockIdx.x, bh = blockIdx.y;
  const int b = bh>>4, h = bh&15;
  const int q0 = qt*64;
  const int lr = l&15, lg = l>>4;

  const bf16* qrow = Qg + (size_t)(b*SEQL + q0 + w*16 + lr)*DM + h*HDIM + lg*8;
  short8 qf0 = *(const short8*)(qrow);
  short8 qf1 = *(const short8*)(qrow + 32);

  const f32x4 vzero = {0.f,0.f,0.f,0.f};
  f32x4 Oa[4];
  float mrow[4], lrow[4];
  #pragma unroll
  for (int j=0;j<4;j++) Oa[j] = vzero;
  #pragma unroll
  for (int r=0;r<4;r++){ mrow[r] = -INFINITY; lrow[r] = 0.f; }

  const int ntiles = CAUSAL ? (qt+1) : (SEQL/64);
  const int c0 = tid, c1 = tid + 256;
  const int r0_ = c0>>3, o0_ = (c0&7)*8, r1_ = c1>>3, o1_ = (c1&7)*8;

  short8 s0,s1,s2,s3;
  {
    s0 = *(const short8*)(Kg + (size_t)(b*SEQL + r0_)*DM + h*HDIM + o0_);
    s1 = *(const short8*)(Kg + (size_t)(b*SEQL + r1_)*DM + h*HDIM + o1_);
    s2 = *(const short8*)(Vt + ((size_t)bh*HDIM + r0_)*SEQL + o0_);
    s3 = *(const short8*)(Vt + ((size_t)bh*HDIM + r1_)*SEQL + o1_);
  }

  for (int t=0; t<ntiles; ++t) {
    __syncthreads();
    *(short8*)(Ks + r0_*PADK + o0_) = s0;
    *(short8*)(Ks + r1_*PADK + o1_) = s1;
    *(short8*)(Vs + r0_*PADK + o0_) = s2;
    *(short8*)(Vs + r1_*PADK + o1_) = s3;
    __syncthreads();
    if (t+1 < ntiles) {
      const int kv1 = (t+1)*64;
      s0 = *(const short8*)(Kg + (size_t)(b*SEQL + kv1 + r0_)*DM + h*HDIM + o0_);
      s1 = *(const short8*)(Kg + (size_t)(b*SEQL + kv1 + r1_)*DM + h*HDIM + o1_);
      s2 = *(const short8*)(Vt + ((size_t)bh*HDIM + r0_)*SEQL + kv1 + o0_);
      s3 = *(const short8*)(Vt + ((size_t)bh*HDIM + r1_)*SEQL + kv1 + o1_);
    }

    f32x4 sa[4];
    #pragma unroll
    for (int jg=0;jg<4;jg++) {
      short8 kb0 = *(const short8*)(Ks + (jg*16+lr)*PADK + lg*8);
      short8 kb1 = *(const short8*)(Ks + (jg*16+lr)*PADK + 32 + lg*8);
      sa[jg] = __builtin_amdgcn_mfma_f32_16x16x32_bf16(qf0, kb0, vzero, 0,0,0);
      sa[jg] = __builtin_amdgcn_mfma_f32_16x16x32_bf16(qf1, kb1, sa[jg], 0,0,0);
    }

    float pv[4][4];
    #pragma unroll
    for (int jg=0;jg<4;jg++)
      #pragma unroll
      for (int r=0;r<4;r++) {
        float sv = sa[jg][r]*0.125f;
        if (CAUSAL && t==ntiles-1) {
          if (jg*16+lr > w*16+lg*4+r) sv = -INFINITY;
        }
        pv[jg][r] = sv;
      }
    float tm[4], sf[4], rs[4];
    #pragma unroll
    for (int r=0;r<4;r++) {
      float mx = fmaxf(fmaxf(pv[0][r],pv[1][r]), fmaxf(pv[2][r],pv[3][r]));
      #pragma unroll
      for (int o=1;o<16;o<<=1) mx = fmaxf(mx, __shfl_xor(mx, o));
      tm[r] = fmaxf(mrow[r], mx);
      sf[r] = __expf(mrow[r]-tm[r]);
      mrow[r] = tm[r];
    }
    #pragma unroll
    for (int r=0;r<4;r++) {
      float acc = 0.f;
      #pragma unroll
      for (int jg=0;jg<4;jg++) { float e = __expf(pv[jg][r]-tm[r]); pv[jg][r]=e; acc += e; }
      #pragma unroll
      for (int o=1;o<16;o<<=1) acc += __shfl_xor(acc, o);
      rs[r] = acc;
      lrow[r] = lrow[r]*sf[r] + rs[r];
    }
    #pragma unroll
    for (int jg=0;jg<4;jg++)
      #pragma unroll
      for (int r=0;r<4;r++) Oa[jg][r] *= sf[r];

    bf16* pw = Ps + w*16*PADK;
    #pragma unroll
    for (int jg=0;jg<4;jg++)
      #pragma unroll
      for (int r=0;r<4;r++)
        pw[(lg*4+r)*PADK + jg*16+lr] = __float2bfloat16(pv[jg][r]);
    asm volatile("s_waitcnt lgkmcnt(0)" ::: "memory");
    __builtin_amdgcn_sched_barrier(0);
    short8 pa0 = *(const short8*)(pw + lr*PADK + lg*8);
    short8 pa1 = *(const short8*)(pw + lr*PADK + 32 + lg*8);
    #pragma unroll
    for (int jg=0;jg<4;jg++) {
      short8 vb0 = *(const short8*)(Vs + (jg*16+lr)*PADK + lg*8);
      short8 vb1 = *(const short8*)(Vs + (jg*16+lr)*PADK + 32 + lg*8);
      Oa[jg] = __builtin_amdgcn_mfma_f32_16x16x32_bf16(pa0, vb0, Oa[jg], 0,0,0);
      Oa[jg] = __builtin_amdgcn_mfma_f32_16x16x32_bf16(pa1, vb1, Oa[jg], 0,0,0);
    }
  }

  #pragma unroll
  for (int r=0;r<4;r++) {
    const float inv = 1.f/lrow[r];
    const size_t rb = (size_t)(b*SEQL + q0 + w*16 + lg*4 + r)*DM + h*HDIM;
    #pragma unroll
    for (int jg=0;jg<4;jg++)
      Og[rb + jg*16 + lr] = __float2bfloat16(Oa[jg][r]*inv);
  }
}

// ---------------- embedding + pos-enc AND enc f32->bf16 (merged prologue) ----------
__global__ __launch_bounds__(256) void embed2_k(const int* __restrict__ dec, const float* __restrict__ emb,
    const float* __restrict__ enc, float* __restrict__ x32, bf16* __restrict__ x16,
    bf16* __restrict__ enc16)
{
  const int bid = blockIdx.x;
  if (bid < 8192) {
    const int idx = bid*256 + threadIdx.x;
    const int d = idx & (DM-1), tok = idx >> 10, s = tok & (SEQL-1);
    const float e = emb[(size_t)dec[tok]*DM + d];
    const float den = powf(10000.f, (float)(d & ~1) * (1.f/(float)DM));
    const float ang = (float)s / den;
    const float pe = (d&1) ? cosf(ang) : sinf(ang);
    const float vv = e + pe;
    x32[idx] = vv; x16[idx] = __float2bfloat16(vv);
  } else {
    const int i = (bid-8192)*256 + threadIdx.x;
    enc16[i] = __float2bfloat16(enc[i]);
  }
}

// ---------------- weight transpose + f32->bf16: dst[N][K] = src[K][N] ----------------
__global__ __launch_bounds__(256) void trans_k(const float* __restrict__ src, bf16* __restrict__ dst, int K, int N)
{
  __shared__ float t[32][33];
  const int n0 = blockIdx.x*32, k0 = blockIdx.y*32;
  const int tx = threadIdx.x&31, ty = threadIdx.x>>5;
  #pragma unroll
  for (int i=0;i<4;i++) t[ty+i*8][tx] = src[(size_t)(k0+ty+i*8)*N + n0+tx];
  __syncthreads();
  #pragma unroll
  for (int i=0;i<4;i++) dst[(size_t)(n0+ty+i*8)*K + k0+tx] = __float2bfloat16(t[tx][ty+i*8]);
}

// ---------------- per-layer multi-matrix transpose ----------------
struct TPack { const float* src[10]; bf16* dst[10]; int K[10]; int N[10]; int tile0[10]; };
__global__ __launch_bounds__(256) void transm_k(TPack p)
{
  __shared__ float t[32][33];
  const int id = blockIdx.x;
  int mi = 0;
  #pragma unroll
  for (int i=1;i<10;i++) if (id >= p.tile0[i]) mi = i;
  const float* src = p.src[mi]; bf16* dst = p.dst[mi];
  const int K = p.K[mi], N = p.N[mi];
  const int local = id - p.tile0[mi];
  const int ntn = N >> 5;
  const int nt = local % ntn, kt = local / ntn;
  const int n0 = nt*32, k0 = kt*32;
  const int tx = threadIdx.x&31, ty = threadIdx.x>>5;
  #pragma unroll
  for (int i=0;i<4;i++) t[ty+i*8][tx] = src[(size_t)(k0+ty+i*8)*N + n0+tx];
  __syncthreads();
  #pragma unroll
  for (int i=0;i<4;i++) dst[(size_t)(n0+ty+i*8)*K + k0+tx] = __float2bfloat16(t[tx][ty+i*8]);
}

// ---------------- upfront bias packing: [L][ sa_q,sa_k,sa_v, ca_q,ca_k,ca_v ][1024] ----
struct BiasSrc { const float* s[6]; float* out; };
__global__ __launch_bounds__(256) void biaspack_k(BiasSrc p)
{
  const int i = blockIdx.x*256 + threadIdx.x;          // < L*6*1024
  const int l = i / 6144, j = i - l*6144;
  const int m = j >> 10, c = j & 1023;
  p.out[i] = p.s[m][(size_t)l*DM + c];
}

// ---------------- fused residual-add + bias + K-split-sum + LayerNorm ----------------
__global__ __launch_bounds__(256) void ln_k(const float* __restrict__ a, const float* __restrict__ a2,
    const float* __restrict__ gb, const float* __restrict__ r,
    const float* __restrict__ g, const float* __restrict__ be,
    float* __restrict__ y32, bf16* __restrict__ y16)
{
  const int row = blockIdx.x, t = threadIdx.x;
  const size_t base = (size_t)row*DM;
  float v[4]; float s = 0.f;
  #pragma unroll
  for (int i=0;i<4;i++){ int c=t+i*256; v[i] = a[base+c] + a2[base+c] + gb[c] + r[base+c]; s += v[i]; }
  __shared__ float red[8];
  #pragma unroll
  for (int o=32;o>0;o>>=1) s += __shfl_down(s,o);
  if ((t&63)==0) red[t>>6]=s;
  __syncthreads();
  const float mean = (red[0]+red[1]+red[2]+red[3]) * (1.f/1024.f);
  float vs = 0.f;
  #pragma unroll
  for (int i=0;i<4;i++){ float d=v[i]-mean; vs += d*d; }
  #pragma unroll
  for (int o=32;o>0;o>>=1) vs += __shfl_down(vs,o);
  if ((t&63)==0) red[4+(t>>6)]=vs;
  __syncthreads();
  const float var = (red[4]+red[5]+red[6]+red[7]) * (1.f/1024.f);
  const float rstd = rsqrtf(var + 1e-10f);
  #pragma unroll
  for (int i=0;i<4;i++){
    int c=t+i*256;
    float y = g[c]*(v[i]-mean)*rstd + be[c];
    y32[base+c] = y; y16[base+c] = __float2bfloat16(y);
  }
}

extern "C" void kernel_launch(void* const* d_in, const int* in_sizes, int n_in,
                              void* d_out, int out_size, void* d_ws, size_t ws_size,
                              hipStream_t stream)
{
  (void)in_sizes; (void)n_in; (void)out_size;
  const int*   dec    = (const int*)  d_in[0];
  const float* enc    = (const float*)d_in[1];
  const float* emb    = (const float*)d_in[4];
  const float* sa_w[4] = { (const float*)d_in[5], (const float*)d_in[7], (const float*)d_in[9],  (const float*)d_in[11] };
  const float* sa_b[4] = { (const float*)d_in[6], (const float*)d_in[8], (const float*)d_in[10], (const float*)d_in[12] };
  const float* ca_w[4] = { (const float*)d_in[13], (const float*)d_in[15], (const float*)d_in[17], (const float*)d_in[19] };
  const float* ca_b[4] = { (const float*)d_in[14], (const float*)d_in[16], (const float*)d_in[18], (const float*)d_in[20] };
  const float* ffn_w1 = (const float*)d_in[21];
  const float* ffn_b1 = (const float*)d_in[22];
  const float* ffn_w2 = (const float*)d_in[23];
  const float* ffn_b2 = (const float*)d_in[24];
  const float* ln_g[3] = { (const float*)d_in[25], (const float*)d_in[27], (const float*)d_in[29] };
  const float* ln_b[3] = { (const float*)d_in[26], (const float*)d_in[28], (const float*)d_in[30] };
  const float* w_out  = (const float*)d_in[31];
  const float* b_out  = (const float*)d_in[32];
  float* out = (float*)d_out;

  char* p = (char*)d_ws;
  auto alloc = [&](size_t b)->char* { char* r=p; p += (b+255)&~(size_t)255; return r; };
  bf16* x16   = (bf16*)alloc((size_t)NTOKC*DM*2);
  bf16* enc16 = (bf16*)alloc((size_t)NTOKC*DM*2);
  bf16* qkv   = (bf16*)alloc((size_t)3*NTOKC*DM*2);
  bf16* ctx   = (bf16*)alloc((size_t)NTOKC*DM*2);
  bf16* vt    = (bf16*)alloc((size_t)64*HDIM*SEQL*2);
  bf16* mid   = (bf16*)alloc((size_t)NTOKC*FFDIM*2);
  bf16* wtA   = (bf16*)alloc((size_t)8*DM*DM*2);
  bf16* wtF1  = (bf16*)alloc((size_t)FFDIM*DM*2);
  bf16* wtF2  = (bf16*)alloc((size_t)DM*FFDIM*2);
  bf16* wtO   = (bf16*)alloc((size_t)VOCAB*DM*2);
  float* x32  = (float*)alloc((size_t)NTOKC*DM*4);
  float* aout = (float*)alloc((size_t)2*NTOKC*DM*4);   // two K-split halves
  float* biasAll = (float*)alloc((size_t)NLAYERS*6*DM*4);
  if ((size_t)(p - (char*)d_ws) > ws_size) return;
  float* aout2 = aout + (size_t)NTOKC*DM;

  embed2_k<<<16384,256,0,stream>>>(dec, emb, enc, x32, x16, enc16);
  trans_k<<<dim3(VOCAB/32, DM/32),256,0,stream>>>(w_out, wtO, DM, VOCAB);
  {
    BiasSrc bs;
    bs.s[0]=sa_b[0]; bs.s[1]=sa_b[1]; bs.s[2]=sa_b[2];
    bs.s[3]=ca_b[0]; bs.s[4]=ca_b[1]; bs.s[5]=ca_b[2];
    bs.out = biasAll;
    biaspack_k<<<(NLAYERS*6*DM)/256,256,0,stream>>>(bs);
  }

  for (int l=0; l<NLAYERS; ++l) {
    {
      TPack tp;
      for (int i=0;i<4;i++){ tp.src[i]   = sa_w[i] + (size_t)l*DM*DM; tp.dst[i]   = wtA + (size_t)i*DM*DM;
                             tp.K[i]=DM; tp.N[i]=DM; tp.tile0[i]=i*1024; }
      for (int i=0;i<4;i++){ tp.src[4+i] = ca_w[i] + (size_t)l*DM*DM; tp.dst[4+i] = wtA + (size_t)(4+i)*DM*DM;
                             tp.K[4+i]=DM; tp.N[4+i]=DM; tp.tile0[4+i]=(4+i)*1024; }
      tp.src[8]=ffn_w1 + (size_t)l*DM*FFDIM; tp.dst[8]=wtF1; tp.K[8]=DM; tp.N[8]=FFDIM; tp.tile0[8]=8192;
      tp.src[9]=ffn_w2 + (size_t)l*FFDIM*DM; tp.dst[9]=wtF2; tp.K[9]=FFDIM; tp.N[9]=DM; tp.tile0[9]=12288;
      transm_k<<<16384,256,0,stream>>>(tp);
    }
    const float* biasL = biasAll + (size_t)l*6*DM;

    // ---- self attention: QKV batched (z=3, HH=3 so zh=z; V -> vt) ----
    gemm_k<128,128><<<dim3(128,1,3),256,0,stream>>>(x16, wtA, qkv, biasL,
        DM, DM, DM, DM, 0,0, 0,(long long)DM*DM, 0,(long long)NTOKC*DM, 3, DM, 1.f, 1|4, 16, x16, 9, vt);
    flash_k<1><<<dim3(SEQL/64, 64),256,0,stream>>>(qkv, qkv + (size_t)NTOKC*DM, vt, ctx);
    gemm_k<64,128><<<dim3(256,1,2),256,0,stream>>>(ctx, wtA + (size_t)3*DM*DM, aout, nullptr,
        512, DM, DM, DM, 0,512, 0,512, 0,(long long)NTOKC*DM, 2, 0, 1.f, 0, 32, ctx, 9, nullptr);
    ln_k<<<2048,256,0,stream>>>(aout, aout2, sa_b[3]+l*DM, x32, ln_g[0]+l*DM, ln_b[0]+l*DM, x32, x16);

    // ---- cross attention: Q(x16) + K,V(enc16) merged z=3; V -> vt ----
    gemm_k<128,128><<<dim3(128,1,3),256,0,stream>>>(x16, wtA + (size_t)4*DM*DM, qkv, biasL + 3*DM,
        DM, DM, DM, DM, 0,0, 0,(long long)DM*DM, 0,(long long)NTOKC*DM, 3, DM, 1.f, 1|4, 16, enc16, 1, vt);
    flash_k<0><<<dim3(SEQL/64, 64),256,0,stream>>>(qkv, qkv + (size_t)NTOKC*DM, vt, ctx);
    gemm_k<64,128><<<dim3(256,1,2),256,0,stream>>>(ctx, wtA + (size_t)7*DM*DM, aout, nullptr,
        512, DM, DM, DM, 0,512, 0,512, 0,(long long)NTOKC*DM, 2, 0, 1.f, 0, 32, ctx, 9, nullptr);
    ln_k<<<2048,256,0,stream>>>(aout, aout2, ca_b[3]+l*DM, x32, ln_g[1]+l*DM, ln_b[1]+l*DM, x32, x16);

    // ---- ffn ----
    gemm_k<128,128><<<dim3(512,1,1),256,0,stream>>>(x16, wtF1, mid, ffn_b1 + (size_t)l*FFDIM,
        DM, DM, DM, FFDIM, 0,0,0,0,0,0, 1, 0, 1.f, 1|2, 16, x16, 9, nullptr);
    gemm_k<64,128><<<dim3(256,1,2),256,0,stream>>>(mid, wtF2, aout, nullptr,
        2048, FFDIM, FFDIM, DM, 0,2048, 0,2048, 0,(long long)NTOKC*DM, 2, 0, 1.f, 0, 32, mid, 9, nullptr);
    ln_k<<<2048,256,0,stream>>>(aout, aout2, ffn_b2 + (size_t)l*DM, x32, ln_g[2]+l*DM, ln_b[2]+l*DM, x32, x16);
  }

  gemm_k<128,128><<<dim3(4000,1,1),256,0,stream>>>(x16, wtO, out, b_out,
      DM, DM, DM, VOCAB, 0,0,0,0,0,0, 1, 0, 1.f, 0, 16, x16, 9, nullptr);
}

// Round 18
// 1509.640 us; speedup vs baseline: 1.1113x; 1.0065x over previous
//
#include <hip/hip_runtime.h>
#include <hip/hip_bf16.h>
#include <math.h>

using bf16 = __hip_bfloat16;
typedef __attribute__((ext_vector_type(8))) short short8;
typedef __attribute__((ext_vector_type(4))) short s16x4;
typedef __attribute__((ext_vector_type(4))) float f32x4;
typedef __attribute__((ext_vector_type(16))) float f32x16;

#define NTOKC 2048
#define DM 1024
#define SEQL 512
#define NHEADS 16
#define HDIM 64
#define FFDIM 4096
#define NLAYERS 6
#define VOCAB 32000

__device__ __forceinline__ void gld_lds16(const void* g, void* l) {
  __builtin_amdgcn_global_load_lds((__attribute__((address_space(1))) void*)g,
                                   (__attribute__((address_space(3))) void*)l, 16, 0, 0);
}

// ---------------- GEMM: C = A[M,K] * Bt[N,K]^T ----------------
// 32x32x16 MFMA, BK=64 single-buffer, k-XOR swizzle over 8 slots (best 2-phase).
// A2/a2from: per-z A-base switch. flag 4 + zh==2: write V^T into VT[bh][d][s]
// via per-wave LDS transpose instead of C. Launches using flag 4 must use HH=3.
// R15 lesson: weights must be converted per-layer (producer->consumer L3 locality).
template<int BM, int BN>
__global__ __launch_bounds__(256, 3) void gemm_k(
    const bf16* __restrict__ A, const bf16* __restrict__ B, void* __restrict__ Cp,
    const float* __restrict__ bias, int K, int lda, int ldb, int ldc,
    long long sAb, long long sAh, long long sBb, long long sBh,
    long long sCb, long long sCh, int HH, int biasStride, float scale, int flags,
    int mTiles, const bf16* __restrict__ A2, int a2from, bf16* __restrict__ VT)
{
  constexpr int WAM = BM/64;
  constexpr int WAN = 4/WAM;
  constexpr int WN  = BN/WAN;
  constexpr int FM  = 2;
  constexpr int FN  = WN/32;
  constexpr int NCA = (BM*64)/2048;
  constexpr int NCB = (BN*64)/2048;
  __shared__ __align__(16) bf16 Smem[BM*64 + BN*64];
  bf16* As = Smem;
  bf16* Bs = Smem + BM*64;
  const int tid = threadIdx.x, w = tid>>6, l = tid&63;
  const int z = blockIdx.z, zb = z/HH, zh = z - zb*HH;
  const bf16* Abase = (zh >= a2from) ? A2 : A;
  const bf16* Ab = Abase + (size_t)zb*sAb + (size_t)zh*sAh;
  const bf16* Bb = B + (size_t)zb*sBb + (size_t)zh*sBh;

  const int nwg = gridDim.x;
  int o = blockIdx.x, idx = o;
  if ((nwg & 7) == 0) idx = (o & 7) * (nwg >> 3) + (o >> 3);   // XCD-chunked, bijective
  const int mt = idx % mTiles, nt = idx / mTiles;              // m fastest within chunk
  const int m0 = mt*BM, n0 = nt*BN;

  const int wm = w / WAN, wn = w % WAN;
  const int lr = l & 31;
  const int lh = l >> 5;

  f32x16 acc[FM][FN];
  #pragma unroll
  for (int i=0;i<FM;i++)
    #pragma unroll
    for (int j=0;j<FN;j++)
      #pragma unroll
      for (int e=0;e<16;e++) acc[i][j][e] = 0.f;

  int rA[NCA], kA[NCA];
  #pragma unroll
  for (int c=0;c<NCA;c++){ int e=c*2048+tid*8; int r=e>>6, k=e&63; rA[c]=r; kA[c]=k ^ ((r&7)<<3); }
  int rB[NCB], kB[NCB];
  #pragma unroll
  for (int c=0;c<NCB;c++){ int e=c*2048+tid*8; int r=e>>6, k=e&63; rB[c]=r; kB[c]=k ^ ((r&7)<<3); }

  for (int kt=0; kt<K; kt+=64) {
    #pragma unroll
    for (int c=0;c<NCA;c++)
      gld_lds16(Ab + (size_t)(m0+rA[c])*lda + kt + kA[c], (char*)As + c*4096 + w*1024);
    #pragma unroll
    for (int c=0;c<NCB;c++)
      gld_lds16(Bb + (size_t)(n0+rB[c])*ldb + kt + kB[c], (char*)Bs + c*4096 + w*1024);
    __syncthreads();
    #pragma unroll
    for (int kq=0; kq<4; kq++) {
      const int kk = kq*16 + lh*8;
      short8 a_[FM], b_[FN];
      #pragma unroll
      for (int i=0;i<FM;i++) {
        const int row = wm*64 + i*32 + lr;
        a_[i] = *(const short8*)(As + row*64 + (kk ^ ((row&7)<<3)));
      }
      #pragma unroll
      for (int j=0;j<FN;j++) {
        const int row = wn*WN + j*32 + lr;
        b_[j] = *(const short8*)(Bs + row*64 + (kk ^ ((row&7)<<3)));
      }
      #pragma unroll
      for (int i=0;i<FM;i++)
        #pragma unroll
        for (int j=0;j<FN;j++)
          acc[i][j] = __builtin_amdgcn_mfma_f32_32x32x16_bf16(a_[i], b_[j], acc[i][j], 0,0,0);
    }
    __syncthreads();
  }

  const float* brow = bias ? (bias + (size_t)z*biasStride) : nullptr;

  // ---- V^T epilogue: per-wave 64x64 LDS transpose -> VT[bh][d][s] ----
  if (BM==128 && BN==128 && (flags & 4) && zh == 2) {
    bf16* T = Smem + w*4096;                         // own 64x64 region (8 KB)
    #pragma unroll
    for (int i=0;i<FM;i++) {
      #pragma unroll
      for (int j=0;j<FN;j++) {
        const int cl = j*32 + lr;                    // local col (=d) 0..63
        const float bv = brow ? brow[n0 + wn*WN + cl] : 0.f;
        #pragma unroll
        for (int r=0;r<16;r++) {
          const int sl = i*32 + 4*lh + (r&3) + 8*(r>>2);   // local row (=s) 0..63
          T[sl*64 + (cl ^ (sl & 63))] = __float2bfloat16(acc[i][j][r]*scale + bv);
        }
      }
    }
    asm volatile("s_waitcnt lgkmcnt(0)" ::: "memory");   // this wave's ds_writes done
    __builtin_amdgcn_sched_barrier(0);
    const int token0 = m0 + wm*64;
    const int bb = token0 >> 9, sbase = token0 & 511;
    const int h = (n0 + wn*WN) >> 6;                 // one head per wave region
    #pragma unroll
    for (int it=0; it<8; ++it) {
      const int crow = it*8 + (l>>3);                // d
      const int s0 = (l&7)*8;
      short8 v8;
      #pragma unroll
      for (int k=0;k<8;k++) {
        const int s = s0 + k;
        v8[k] = *(const short*)&T[s*64 + (crow ^ (s & 63))];
      }
      *(short8*)(VT + (((size_t)(bb*16 + h)*64 + crow)*512 + sbase + s0)) = v8;
    }
    return;                                          // uniform branch per block
  }

  const bool obf = flags & 1, orl = flags & 2;
  const size_t coff = (size_t)zb*sCb + (size_t)zh*sCh;
  #pragma unroll
  for (int i=0;i<FM;i++) {
    #pragma unroll
    for (int j=0;j<FN;j++) {
      const int col = n0 + wn*WN + j*32 + lr;
      const float bv = brow ? brow[col] : 0.f;
      const int row0 = m0 + wm*64 + i*32 + 4*lh;
      #pragma unroll
      for (int r=0;r<16;r++) {
        const int row = row0 + (r&3) + 8*(r>>2);
        float v = acc[i][j][r]*scale + bv;
        if (orl) v = fmaxf(v, 0.f);
        const size_t off = coff + (size_t)row*ldc + col;
        if (obf) ((bf16*)Cp)[off] = __float2bfloat16(v);
        else     ((float*)Cp)[off] = v;
      }
    }
  }
}

// ---------------- fused flash attention ----------------
// grid: (q-tiles=8, bh=64). 4 waves (256 thr); wave owns 16 q-rows; KV tiles of 64.
// TWO staging chunks per K/V tile (256 thr x 8 elems = rows 0-31; +256 = rows 32-63).
template<int CAUSAL>
__global__ __launch_bounds__(256, 4) void flash_k(
    const bf16* __restrict__ Qg, const bf16* __restrict__ Kg,
    const bf16* __restrict__ Vt, bf16* __restrict__ Og)
{
  constexpr int PADK = 72;
  __shared__ __align__(16) bf16 Ks[64*PADK];
  __shared__ __align__(16) bf16 Vs[64*PADK];
  __shared__ __align__(16) bf16 Ps[4*16*PADK];
  const int tid = threadIdx.x, w = tid>>6, l = tid&63;
  const int qt = blockIdx.x, bh = blockIdx.y;
  const int b = bh>>4, h = bh&15;
  const int q0 = qt*64;
  const int lr = l&15, lg = l>>4;

  const bf16* qrow = Qg + (size_t)(b*SEQL + q0 + w*16 + lr)*DM + h*HDIM + lg*8;
  short8 qf0 = *(const short8*)(qrow);
  short8 qf1 = *(const short8*)(qrow + 32);

  const f32x4 vzero = {0.f,0.f,0.f,0.f};
  f32x4 Oa[4];
  float mrow[4], lrow[4];
  #pragma unroll
  for (int j=0;j<4;j++) Oa[j] = vzero;
  #pragma unroll
  for (int r=0;r<4;r++){ mrow[r] = -INFINITY; lrow[r] = 0.f; }

  const int ntiles = CAUSAL ? (qt+1) : (SEQL/64);
  const int c0 = tid, c1 = tid + 256;
  const int r0_ = c0>>3, o0_ = (c0&7)*8, r1_ = c1>>3, o1_ = (c1&7)*8;

  short8 s0,s1,s2,s3;
  {
    s0 = *(const short8*)(Kg + (size_t)(b*SEQL + r0_)*DM + h*HDIM + o0_);
    s1 = *(const short8*)(Kg + (size_t)(b*SEQL + r1_)*DM + h*HDIM + o1_);
    s2 = *(const short8*)(Vt + ((size_t)bh*HDIM + r0_)*SEQL + o0_);
    s3 = *(const short8*)(Vt + ((size_t)bh*HDIM + r1_)*SEQL + o1_);
  }

  for (int t=0; t<ntiles; ++t) {
    __syncthreads();
    *(short8*)(Ks + r0_*PADK + o0_) = s0;
    *(short8*)(Ks + r1_*PADK + o1_) = s1;
    *(short8*)(Vs + r0_*PADK + o0_) = s2;
    *(short8*)(Vs + r1_*PADK + o1_) = s3;
    __syncthreads();
    if (t+1 < ntiles) {
      const int kv1 = (t+1)*64;
      s0 = *(const short8*)(Kg + (size_t)(b*SEQL + kv1 + r0_)*DM + h*HDIM + o0_);
      s1 = *(const short8*)(Kg + (size_t)(b*SEQL + kv1 + r1_)*DM + h*HDIM + o1_);
      s2 = *(const short8*)(Vt + ((size_t)bh*HDIM + r0_)*SEQL + kv1 + o0_);
      s3 = *(const short8*)(Vt + ((size_t)bh*HDIM + r1_)*SEQL + kv1 + o1_);
    }

    f32x4 sa[4];
    #pragma unroll
    for (int jg=0;jg<4;jg++) {
      short8 kb0 = *(const short8*)(Ks + (jg*16+lr)*PADK + lg*8);
      short8 kb1 = *(const short8*)(Ks + (jg*16+lr)*PADK + 32 + lg*8);
      sa[jg] = __builtin_amdgcn_mfma_f32_16x16x32_bf16(qf0, kb0, vzero, 0,0,0);
      sa[jg] = __builtin_amdgcn_mfma_f32_16x16x32_bf16(qf1, kb1, sa[jg], 0,0,0);
    }

    float pv[4][4];
    #pragma unroll
    for (int jg=0;jg<4;jg++)
      #pragma unroll
      for (int r=0;r<4;r++) {
        float sv = sa[jg][r]*0.125f;
        if (CAUSAL && t==ntiles-1) {
          if (jg*16+lr > w*16+lg*4+r) sv = -INFINITY;
        }
        pv[jg][r] = sv;
      }
    float tm[4], sf[4], rs[4];
    #pragma unroll
    for (int r=0;r<4;r++) {
      float mx = fmaxf(fmaxf(pv[0][r],pv[1][r]), fmaxf(pv[2][r],pv[3][r]));
      #pragma unroll
      for (int o=1;o<16;o<<=1) mx = fmaxf(mx, __shfl_xor(mx, o));
      tm[r] = fmaxf(mrow[r], mx);
      sf[r] = __expf(mrow[r]-tm[r]);
      mrow[r] = tm[r];
    }
    #pragma unroll
    for (int r=0;r<4;r++) {
      float acc = 0.f;
      #pragma unroll
      for (int jg=0;jg<4;jg++) { float e = __expf(pv[jg][r]-tm[r]); pv[jg][r]=e; acc += e; }
      #pragma unroll
      for (int o=1;o<16;o<<=1) acc += __shfl_xor(acc, o);
      rs[r] = acc;
      lrow[r] = lrow[r]*sf[r] + rs[r];
    }
    #pragma unroll
    for (int jg=0;jg<4;jg++)
      #pragma unroll
      for (int r=0;r<4;r++) Oa[jg][r] *= sf[r];

    bf16* pw = Ps + w*16*PADK;
    #pragma unroll
    for (int jg=0;jg<4;jg++)
      #pragma unroll
      for (int r=0;r<4;r++)
        pw[(lg*4+r)*PADK + jg*16+lr] = __float2bfloat16(pv[jg][r]);
    asm volatile("s_waitcnt lgkmcnt(0)" ::: "memory");
    __builtin_amdgcn_sched_barrier(0);
    short8 pa0 = *(const short8*)(pw + lr*PADK + lg*8);
    short8 pa1 = *(const short8*)(pw + lr*PADK + 32 + lg*8);
    #pragma unroll
    for (int jg=0;jg<4;jg++) {
      short8 vb0 = *(const short8*)(Vs + (jg*16+lr)*PADK + lg*8);
      short8 vb1 = *(const short8*)(Vs + (jg*16+lr)*PADK + 32 + lg*8);
      Oa[jg] = __builtin_amdgcn_mfma_f32_16x16x32_bf16(pa0, vb0, Oa[jg], 0,0,0);
      Oa[jg] = __builtin_amdgcn_mfma_f32_16x16x32_bf16(pa1, vb1, Oa[jg], 0,0,0);
    }
  }

  #pragma unroll
  for (int r=0;r<4;r++) {
    const float inv = 1.f/lrow[r];
    const size_t rb = (size_t)(b*SEQL + q0 + w*16 + lg*4 + r)*DM + h*HDIM;
    #pragma unroll
    for (int jg=0;jg<4;jg++)
      Og[rb + jg*16 + lr] = __float2bfloat16(Oa[jg][r]*inv);
  }
}

// ---------------- embedding + pos-enc AND enc f32->bf16 (merged, fast math) ------
__global__ __launch_bounds__(256) void embed2_k(const int* __restrict__ dec, const float* __restrict__ emb,
    const float* __restrict__ enc, float* __restrict__ x32, bf16* __restrict__ x16,
    bf16* __restrict__ enc16)
{
  const int bid = blockIdx.x;
  if (bid < 8192) {
    const int idx = bid*256 + threadIdx.x;
    const int d = idx & (DM-1), tok = idx >> 10, s = tok & (SEQL-1);
    const float e = emb[(size_t)dec[tok]*DM + d];
    // 1/10000^(d2/1024) = exp(-d2 * ln(10000)/1024)
    const float ang = (float)s * __expf((float)(d & ~1) * -0.0089944731f);
    const float pe = (d&1) ? __cosf(ang) : __sinf(ang);
    const float vv = e + pe;
    x32[idx] = vv; x16[idx] = __float2bfloat16(vv);
  } else {
    const int i = (bid-8192)*256 + threadIdx.x;
    enc16[i] = __float2bfloat16(enc[i]);
  }
}

// ---------------- weight transpose + f32->bf16: dst[N][K] = src[K][N] ----------------
__global__ __launch_bounds__(256) void trans_k(const float* __restrict__ src, bf16* __restrict__ dst, int K, int N)
{
  __shared__ float t[32][33];
  const int n0 = blockIdx.x*32, k0 = blockIdx.y*32;
  const int tx = threadIdx.x&31, ty = threadIdx.x>>5;
  #pragma unroll
  for (int i=0;i<4;i++) t[ty+i*8][tx] = src[(size_t)(k0+ty+i*8)*N + n0+tx];
  __syncthreads();
  #pragma unroll
  for (int i=0;i<4;i++) dst[(size_t)(n0+ty+i*8)*K + k0+tx] = __float2bfloat16(t[tx][ty+i*8]);
}

// ---------------- per-layer multi-matrix transpose ----------------
struct TPack { const float* src[10]; bf16* dst[10]; int K[10]; int N[10]; int tile0[10]; };
__global__ __launch_bounds__(256) void transm_k(TPack p)
{
  __shared__ float t[32][33];
  const int id = blockIdx.x;
  int mi = 0;
  #pragma unroll
  for (int i=1;i<10;i++) if (id >= p.tile0[i]) mi = i;
  const float* src = p.src[mi]; bf16* dst = p.dst[mi];
  const int K = p.K[mi], N = p.N[mi];
  const int local = id - p.tile0[mi];
  const int ntn = N >> 5;
  const int nt = local % ntn, kt = local / ntn;
  const int n0 = nt*32, k0 = kt*32;
  const int tx = threadIdx.x&31, ty = threadIdx.x>>5;
  #pragma unroll
  for (int i=0;i<4;i++) t[ty+i*8][tx] = src[(size_t)(k0+ty+i*8)*N + n0+tx];
  __syncthreads();
  #pragma unroll
  for (int i=0;i<4;i++) dst[(size_t)(n0+ty+i*8)*K + k0+tx] = __float2bfloat16(t[tx][ty+i*8]);
}

// ---------------- upfront bias packing: [L][ sa_q,sa_k,sa_v, ca_q,ca_k,ca_v ][1024] ----
struct BiasSrc { const float* s[6]; float* out; };
__global__ __launch_bounds__(256) void biaspack_k(BiasSrc p)
{
  const int i = blockIdx.x*256 + threadIdx.x;          // < L*6*1024
  const int l = i / 6144, j = i - l*6144;
  const int m = j >> 10, c = j & 1023;
  p.out[i] = p.s[m][(size_t)l*DM + c];
}

// ---------------- fused residual-add + bias + K-split-sum + LayerNorm (float4) ----
// v = a + a2 + gbias + r; emits f32 residual + bf16 activation. Thread t owns
// 4 contiguous cols [4t, 4t+4).
__global__ __launch_bounds__(256) void ln_k(const float* __restrict__ a, const float* __restrict__ a2,
    const float* __restrict__ gb, const float* __restrict__ r,
    const float* __restrict__ g, const float* __restrict__ be,
    float* __restrict__ y32, bf16* __restrict__ y16)
{
  const int row = blockIdx.x, t = threadIdx.x;
  const size_t base = (size_t)row*DM + t*4;
  const f32x4 va = *(const f32x4*)(a  + base);
  const f32x4 vb = *(const f32x4*)(a2 + base);
  const f32x4 vr = *(const f32x4*)(r  + base);
  const f32x4 vg = *(const f32x4*)(gb + t*4);
  float v[4]; float s = 0.f;
  #pragma unroll
  for (int i=0;i<4;i++){ v[i] = va[i] + vb[i] + vg[i] + vr[i]; s += v[i]; }
  __shared__ float red[8];
  #pragma unroll
  for (int o=32;o>0;o>>=1) s += __shfl_down(s,o);
  if ((t&63)==0) red[t>>6]=s;
  __syncthreads();
  const float mean = (red[0]+red[1]+red[2]+red[3]) * (1.f/1024.f);
  float vs = 0.f;
  #pragma unroll
  for (int i=0;i<4;i++){ float d=v[i]-mean; vs += d*d; }
  #pragma unroll
  for (int o=32;o>0;o>>=1) vs += __shfl_down(vs,o);
  if ((t&63)==0) red[4+(t>>6)]=vs;
  __syncthreads();
  const float var = (red[4]+red[5]+red[6]+red[7]) * (1.f/1024.f);
  const float rstd = rsqrtf(var + 1e-10f);
  const f32x4 gg = *(const f32x4*)(g  + t*4);
  const f32x4 bb = *(const f32x4*)(be + t*4);
  f32x4 y; s16x4 h;
  #pragma unroll
  for (int i=0;i<4;i++){
    y[i] = gg[i]*(v[i]-mean)*rstd + bb[i];
    bf16 tb = __float2bfloat16(y[i]);
    h[i] = *(const short*)&tb;
  }
  *(f32x4*)(y32 + base) = y;
  *(s16x4*)((short*)y16 + base) = h;
}

extern "C" void kernel_launch(void* const* d_in, const int* in_sizes, int n_in,
                              void* d_out, int out_size, void* d_ws, size_t ws_size,
                              hipStream_t stream)
{
  (void)in_sizes; (void)n_in; (void)out_size;
  const int*   dec    = (const int*)  d_in[0];
  const float* enc    = (const float*)d_in[1];
  const float* emb    = (const float*)d_in[4];
  const float* sa_w[4] = { (const float*)d_in[5], (const float*)d_in[7], (const float*)d_in[9],  (const float*)d_in[11] };
  const float* sa_b[4] = { (const float*)d_in[6], (const float*)d_in[8], (const float*)d_in[10], (const float*)d_in[12] };
  const float* ca_w[4] = { (const float*)d_in[13], (const float*)d_in[15], (const float*)d_in[17], (const float*)d_in[19] };
  const float* ca_b[4] = { (const float*)d_in[14], (const float*)d_in[16], (const float*)d_in[18], (const float*)d_in[20] };
  const float* ffn_w1 = (const float*)d_in[21];
  const float* ffn_b1 = (const float*)d_in[22];
  const float* ffn_w2 = (const float*)d_in[23];
  const float* ffn_b2 = (const float*)d_in[24];
  const float* ln_g[3] = { (const float*)d_in[25], (const float*)d_in[27], (const float*)d_in[29] };
  const float* ln_b[3] = { (const float*)d_in[26], (const float*)d_in[28], (const float*)d_in[30] };
  const float* w_out  = (const float*)d_in[31];
  const float* b_out  = (const float*)d_in[32];
  float* out = (float*)d_out;

  char* p = (char*)d_ws;
  auto alloc = [&](size_t b)->char* { char* r=p; p += (b+255)&~(size_t)255; return r; };
  bf16* x16   = (bf16*)alloc((size_t)NTOKC*DM*2);
  bf16* enc16 = (bf16*)alloc((size_t)NTOKC*DM*2);
  bf16* qkv   = (bf16*)alloc((size_t)3*NTOKC*DM*2);
  bf16* ctx   = (bf16*)alloc((size_t)NTOKC*DM*2);
  bf16* vt    = (bf16*)alloc((size_t)64*HDIM*SEQL*2);
  bf16* mid   = (bf16*)alloc((size_t)NTOKC*FFDIM*2);
  bf16* wtA   = (bf16*)alloc((size_t)8*DM*DM*2);
  bf16* wtF1  = (bf16*)alloc((size_t)FFDIM*DM*2);
  bf16* wtF2  = (bf16*)alloc((size_t)DM*FFDIM*2);
  bf16* wtO   = (bf16*)alloc((size_t)VOCAB*DM*2);
  float* x32  = (float*)alloc((size_t)NTOKC*DM*4);
  float* aout = (float*)alloc((size_t)2*NTOKC*DM*4);   // two K-split halves
  float* biasAll = (float*)alloc((size_t)NLAYERS*6*DM*4);
  if ((size_t)(p - (char*)d_ws) > ws_size) return;
  float* aout2 = aout + (size_t)NTOKC*DM;

  embed2_k<<<16384,256,0,stream>>>(dec, emb, enc, x32, x16, enc16);
  trans_k<<<dim3(VOCAB/32, DM/32),256,0,stream>>>(w_out, wtO, DM, VOCAB);
  {
    BiasSrc bs;
    bs.s[0]=sa_b[0]; bs.s[1]=sa_b[1]; bs.s[2]=sa_b[2];
    bs.s[3]=ca_b[0]; bs.s[4]=ca_b[1]; bs.s[5]=ca_b[2];
    bs.out = biasAll;
    biaspack_k<<<(NLAYERS*6*DM)/256,256,0,stream>>>(bs);
  }

  for (int l=0; l<NLAYERS; ++l) {
    {
      TPack tp;
      for (int i=0;i<4;i++){ tp.src[i]   = sa_w[i] + (size_t)l*DM*DM; tp.dst[i]   = wtA + (size_t)i*DM*DM;
                             tp.K[i]=DM; tp.N[i]=DM; tp.tile0[i]=i*1024; }
      for (int i=0;i<4;i++){ tp.src[4+i] = ca_w[i] + (size_t)l*DM*DM; tp.dst[4+i] = wtA + (size_t)(4+i)*DM*DM;
                             tp.K[4+i]=DM; tp.N[4+i]=DM; tp.tile0[4+i]=(4+i)*1024; }
      tp.src[8]=ffn_w1 + (size_t)l*DM*FFDIM; tp.dst[8]=wtF1; tp.K[8]=DM; tp.N[8]=FFDIM; tp.tile0[8]=8192;
      tp.src[9]=ffn_w2 + (size_t)l*FFDIM*DM; tp.dst[9]=wtF2; tp.K[9]=FFDIM; tp.N[9]=DM; tp.tile0[9]=12288;
      transm_k<<<16384,256,0,stream>>>(tp);
    }
    const float* biasL = biasAll + (size_t)l*6*DM;

    // ---- self attention: QKV batched (z=3, HH=3 so zh=z; V -> vt) ----
    gemm_k<128,128><<<dim3(128,1,3),256,0,stream>>>(x16, wtA, qkv, biasL,
        DM, DM, DM, DM, 0,0, 0,(long long)DM*DM, 0,(long long)NTOKC*DM, 3, DM, 1.f, 1|4, 16, x16, 9, vt);
    flash_k<1><<<dim3(SEQL/64, 64),256,0,stream>>>(qkv, qkv + (size_t)NTOKC*DM, vt, ctx);
    gemm_k<64,128><<<dim3(256,1,2),256,0,stream>>>(ctx, wtA + (size_t)3*DM*DM, aout, nullptr,
        512, DM, DM, DM, 0,512, 0,512, 0,(long long)NTOKC*DM, 2, 0, 1.f, 0, 32, ctx, 9, nullptr);
    ln_k<<<2048,256,0,stream>>>(aout, aout2, sa_b[3]+l*DM, x32, ln_g[0]+l*DM, ln_b[0]+l*DM, x32, x16);

    // ---- cross attention: Q(x16) + K,V(enc16) merged z=3; V -> vt ----
    gemm_k<128,128><<<dim3(128,1,3),256,0,stream>>>(x16, wtA + (size_t)4*DM*DM, qkv, biasL + 3*DM,
        DM, DM, DM, DM, 0,0, 0,(long long)DM*DM, 0,(long long)NTOKC*DM, 3, DM, 1.f, 1|4, 16, enc16, 1, vt);
    flash_k<0><<<dim3(SEQL/64, 64),256,0,stream>>>(qkv, qkv + (size_t)NTOKC*DM, vt, ctx);
    gemm_k<64,128><<<dim3(256,1,2),256,0,stream>>>(ctx, wtA + (size_t)7*DM*DM, aout, nullptr,
        512, DM, DM, DM, 0,512, 0,512, 0,(long long)NTOKC*DM, 2, 0, 1.f, 0, 32, ctx, 9, nullptr);
    ln_k<<<2048,256,0,stream>>>(aout, aout2, ca_b[3]+l*DM, x32, ln_g[1]+l*DM, ln_b[1]+l*DM, x32, x16);

    // ---- ffn ----
    gemm_k<128,128><<<dim3(512,1,1),256,0,stream>>>(x16, wtF1, mid, ffn_b1 + (size_t)l*FFDIM,
        DM, DM, DM, FFDIM, 0,0,0,0,0,0, 1, 0, 1.f, 1|2, 16, x16, 9, nullptr);
    gemm_k<64,128><<<dim3(256,1,2),256,0,stream>>>(mid, wtF2, aout, nullptr,
        2048, FFDIM, FFDIM, DM, 0,2048, 0,2048, 0,(long long)NTOKC*DM, 2, 0, 1.f, 0, 32, mid, 9, nullptr);
    ln_k<<<2048,256,0,stream>>>(aout, aout2, ffn_b2 + (size_t)l*DM, x32, ln_g[2]+l*DM, ln_b[2]+l*DM, x32, x16);
  }

  gemm_k<128,128><<<dim3(4000,1,1),256,0,stream>>>(x16, wtO, out, b_out,
      DM, DM, DM, VOCAB, 0,0,0,0,0,0, 1, 0, 1.f, 0, 16, x16, 9, nullptr);
}